// Round 8
// baseline (185.204 us; speedup 1.0000x reference)
//
#include <hip/hip_runtime.h>

typedef _Float16 f16_t;
typedef _Float16 f16x4 __attribute__((ext_vector_type(4)));
typedef _Float16 f16x8 __attribute__((ext_vector_type(8)));
typedef float f32x4 __attribute__((ext_vector_type(4)));

#define T_DIM 2048
#define B_DIM 8
#define C_DIM 1024
#define H_DIM 128

__device__ __forceinline__ void gload16(const void* g, void* l) {
  __builtin_amdgcn_global_load_lds((const __attribute__((address_space(1))) void*)g,
                                   (__attribute__((address_space(3))) void*)l, 16, 0, 0);
}

// ---------- Kernel 0: W [C][H] fp32 -> Wt [H][C] f16 (scale folded into Wq) ----------
__global__ __launch_bounds__(256) void wprep_kernel(
    const float* __restrict__ Wq, const float* __restrict__ Wk, const float* __restrict__ Wv,
    f16_t* __restrict__ Wtq, f16_t* __restrict__ Wtk, f16_t* __restrict__ Wtv) {
  int z = blockIdx.x;
  const float* src = (z == 0) ? Wq : (z == 1) ? Wk : Wv;
  f16_t* dst = (z == 0) ? Wtq : (z == 1) ? Wtk : Wtv;
  // scale = log2(e) / sqrt(128) folded into Wq so attention scores are in exp2 domain
  float sc = (z == 0) ? (1.4426950408889634f * 0.08838834764831845f) : 1.0f;
  int base = blockIdx.y * 2048;
  for (int i = threadIdx.x; i < 2048; i += 256) {
    int idx = base + i;
    int c = idx >> 7, h = idx & 127;
    dst[h * C_DIM + c] = (f16_t)(src[idx] * sc);
  }
}

// ---------- Kernel 1: projections — high-occupancy small-tile GEMM ----------
// Parallelism fix: 32-row tiles, grid (512,3) = 1536 blocks = 6 blocks/CU, LDS only
// 4.6 KB (A tile, padded [32][72]) -> ~24 waves/CU resident. W fragments read DIRECT
// from global (256 KB, L2-hot across all blocks; round-3-proven pattern). Two-barrier
// K-loop as round 2. BW scales with resident waves (cvt diagnostic: 65% occ = 3.4 TB/s).
// z=0: Qh[b][t][h], z=1: Kh[b][t][h], z=2: Vt[b][o][t]
__global__ __launch_bounds__(256) void proj_kernel(
    const float* __restrict__ qin, const float* __restrict__ kin, const float* __restrict__ vin,
    const f16_t* __restrict__ Wtq, const f16_t* __restrict__ Wtk, const f16_t* __restrict__ Wtv,
    f16_t* __restrict__ Qh, f16_t* __restrict__ Kh, f16_t* __restrict__ Vt) {
  int z = blockIdx.y;
  const float* src = (z == 0) ? qin : (z == 1) ? kin : vin;
  const f16_t* Wt = (z == 0) ? Wtq : (z == 1) ? Wtk : Wtv;

  __shared__ f16_t Alds[32][72];  // 4.6 KB

  int tid = threadIdx.x;
  int wid = tid >> 6, lane = tid & 63, g = lane >> 4, lr = lane & 15;
  int wr = (wid & 1) * 16, wc = (wid >> 1) * 64;
  int rbase = blockIdx.x * 32;
  int arow = tid >> 3, acol = (tid & 7) * 8;

  const float* arp = src + (size_t)(rbase + arow) * C_DIM + acol;
  const f16_t* wb = Wt + (size_t)(wc + lr) * C_DIM + g * 8;  // + cf*16*C + kb + k2*32

  const f32x4 z4 = {0.0f, 0.0f, 0.0f, 0.0f};
  f32x4 acc[4];
#pragma unroll
  for (int j = 0; j < 4; ++j) acc[j] = z4;

  for (int kb = 0; kb < C_DIM; kb += 64) {
    __syncthreads();  // prior step's readers done
    // stage A: 32 rows x 64 k fp32 -> f16, each thread one f16x8
    f32x4 alo = *(const f32x4*)(arp + kb);
    f32x4 ahi = *(const f32x4*)(arp + kb + 4);
    f16x8 h8;
    h8[0] = (f16_t)alo[0]; h8[1] = (f16_t)alo[1]; h8[2] = (f16_t)alo[2]; h8[3] = (f16_t)alo[3];
    h8[4] = (f16_t)ahi[0]; h8[5] = (f16_t)ahi[1]; h8[6] = (f16_t)ahi[2]; h8[7] = (f16_t)ahi[3];
    *(f16x8*)&Alds[arow][acol] = h8;
    __syncthreads();
#pragma unroll
    for (int k2 = 0; k2 < 2; ++k2) {
      f16x8 af = *(const f16x8*)&Alds[wr + lr][k2 * 32 + g * 8];
      f16x8 wf[4];
#pragma unroll
      for (int cf = 0; cf < 4; ++cf)
        wf[cf] = *(const f16x8*)(wb + (size_t)cf * 16 * C_DIM + kb + k2 * 32);
#pragma unroll
      for (int cf = 0; cf < 4; ++cf)
        acc[cf] = __builtin_amdgcn_mfma_f32_16x16x32_f16(af, wf[cf], acc[cf], 0, 0, 0);
    }
  }

  if (z < 2) {
    f16_t* outp = (z == 0) ? Qh : Kh;
#pragma unroll
    for (int cf = 0; cf < 4; ++cf)
#pragma unroll
      for (int r = 0; r < 4; ++r) {
        int rg = rbase + wr + g * 4 + r;
        int t = rg >> 3, bb = rg & 7;
        int h = wc + cf * 16 + lr;
        outp[(size_t)((bb << 11) | t) * H_DIM + h] = (f16_t)acc[cf][r];
      }
  } else {
#pragma unroll
    for (int cf = 0; cf < 4; ++cf)
#pragma unroll
      for (int r = 0; r < 4; ++r) {
        int rg = rbase + wr + g * 4 + r;
        int t = rg >> 3, bb = rg & 7;
        int h = wc + cf * 16 + lr;
        Vt[((size_t)bb << 18) | ((size_t)h << 11) | (size_t)t] = (f16_t)acc[cf][r];
      }
  }
}

// ---------- Kernel 2: causal flash attention, LDS-staged K/V (unchanged) ----------
__global__ __launch_bounds__(256) void attn_kernel(
    const f16_t* __restrict__ Qh, const f16_t* __restrict__ Kh, const f16_t* __restrict__ Vt,
    float* __restrict__ out) {
  int b = blockIdx.x;
  int qt = (gridDim.y - 1) - blockIdx.y;
  int tid = threadIdx.x;
  int wid = tid >> 6, lane = tid & 63, g = lane >> 4, lr = lane & 15;
  int qlo = qt * 64 + wid * 16;

  __shared__ f16_t Kl[64 * 128];
  __shared__ f16_t Vl[2][128 * 64];
  __shared__ f16_t Plds[4][16][72];

  const f16_t* Qb = Qh + ((size_t)b << 11) * H_DIM;
  const f16_t* Kb = Kh + ((size_t)b << 11) * H_DIM;
  const f16_t* Vb = Vt + ((size_t)b << 18);

  f16x8 qa[4];
#pragma unroll
  for (int c = 0; c < 4; ++c)
    qa[c] = *(const f16x8*)&Qb[(size_t)(qlo + lr) * H_DIM + c * 32 + g * 8];

  const f32x4 z4 = {0.0f, 0.0f, 0.0f, 0.0f};
  float mrow[4], lsum[4];
  f32x4 acc[8];
#pragma unroll
  for (int r = 0; r < 4; ++r) { mrow[r] = -1e30f; lsum[r] = 0.0f; }
#pragma unroll
  for (int of = 0; of < 8; ++of) acc[of] = z4;

  int ntiles = qt + 1;

  auto stageK = [&](int kt) {
    const char* base = (const char*)(Kb + (size_t)(kt * 64) * H_DIM);
#pragma unroll
    for (int i = 0; i < 4; ++i) {
      int chunk = wid * 4 + i;
      int q = chunk * 1024 + lane * 16;
      int p = q ^ (((q >> 8) & 7) << 4);
      gload16(base + p, (char*)&Kl[0] + q);
    }
  };
  auto stageV = [&](int bufi, int kt) {
#pragma unroll
    for (int i = 0; i < 4; ++i) {
      int chunk = wid * 4 + i;
      int q = chunk * 1024 + lane * 16;
      int p = q ^ (((q >> 7) & 7) << 4);
      int row = p >> 7;
      int colb = p & 127;
      const char* src = (const char*)(Vb + (size_t)row * T_DIM + kt * 64) + colb;
      gload16(src, (char*)&Vl[bufi][0] + q);
    }
  };

  stageK(0);
  stageV(0, 0);
  __syncthreads();
  int vcur = 0;

  for (int kt = 0; kt < ntiles; ++kt) {
    int kb = kt * 64;
    bool more = (kt + 1 < ntiles);
    if (more) stageV(vcur ^ 1, kt + 1);

    f32x4 s[4];
#pragma unroll
    for (int cf = 0; cf < 4; ++cf) s[cf] = z4;
    const char* Kbuf = (const char*)&Kl[0];
#pragma unroll
    for (int cf = 0; cf < 4; ++cf) {
      int row = cf * 16 + lr;
#pragma unroll
      for (int c = 0; c < 4; ++c) {
        int linb = row * 256 + c * 64 + g * 16;
        f16x8 kf = *(const f16x8*)(Kbuf + (linb ^ ((row & 7) << 4)));
        s[cf] = __builtin_amdgcn_mfma_f32_16x16x32_f16(qa[c], kf, s[cf], 0, 0, 0);
      }
    }
    __syncthreads();
    if (more) stageK(kt + 1);

    if (kb + 63 > qlo) {
#pragma unroll
      for (int cf = 0; cf < 4; ++cf) {
        int kcol = kb + cf * 16 + lr;
#pragma unroll
        for (int r = 0; r < 4; ++r)
          if (kcol > qlo + g * 4 + r) s[cf][r] = -1e30f;
      }
    }
    float cand[4], mnew[4], al[4], rs[4];
#pragma unroll
    for (int r = 0; r < 4; ++r)
      cand[r] = fmaxf(fmaxf(s[0][r], s[1][r]), fmaxf(s[2][r], s[3][r]));
#pragma unroll
    for (int d = 1; d <= 8; d <<= 1)
#pragma unroll
      for (int r = 0; r < 4; ++r)
        cand[r] = fmaxf(cand[r], __shfl_xor(cand[r], d));
    float p[4][4];
#pragma unroll
    for (int r = 0; r < 4; ++r) {
      mnew[r] = fmaxf(mrow[r], cand[r]);
      al[r] = exp2f(mrow[r] - mnew[r]);
      mrow[r] = mnew[r];
    }
#pragma unroll
    for (int cf = 0; cf < 4; ++cf)
#pragma unroll
      for (int r = 0; r < 4; ++r)
        p[cf][r] = exp2f(s[cf][r] - mnew[r]);
#pragma unroll
    for (int r = 0; r < 4; ++r)
      rs[r] = (p[0][r] + p[1][r]) + (p[2][r] + p[3][r]);
#pragma unroll
    for (int d = 1; d <= 8; d <<= 1)
#pragma unroll
      for (int r = 0; r < 4; ++r)
        rs[r] += __shfl_xor(rs[r], d);
#pragma unroll
    for (int r = 0; r < 4; ++r)
      lsum[r] = lsum[r] * al[r] + rs[r];
#pragma unroll
    for (int of = 0; of < 8; ++of)
#pragma unroll
      for (int r = 0; r < 4; ++r)
        acc[of][r] *= al[r];
#pragma unroll
    for (int cf = 0; cf < 4; ++cf)
#pragma unroll
      for (int r = 0; r < 4; ++r)
        Plds[wid][g * 4 + r][cf * 16 + lr] = (f16_t)p[cf][r];
    asm volatile("s_waitcnt lgkmcnt(0)" ::: "memory");
    __builtin_amdgcn_sched_barrier(0);
    f16x8 pa[2];
#pragma unroll
    for (int c = 0; c < 2; ++c)
      pa[c] = *(const f16x8*)&Plds[wid][lr][c * 32 + g * 8];

    const char* Vbuf = (const char*)&Vl[vcur][0];
#pragma unroll
    for (int c = 0; c < 2; ++c)
#pragma unroll
      for (int of = 0; of < 8; ++of) {
        int row = of * 16 + lr;
        int linb = row * 128 + c * 64 + g * 16;
        f16x8 vf = *(const f16x8*)(Vbuf + (linb ^ ((row & 7) << 4)));
        acc[of] = __builtin_amdgcn_mfma_f32_16x16x32_f16(pa[c], vf, acc[of], 0, 0, 0);
      }
    __syncthreads();
    vcur ^= 1;
  }

#pragma unroll
  for (int of = 0; of < 8; ++of)
#pragma unroll
    for (int r = 0; r < 4; ++r) {
      int qr = qlo + g * 4 + r;
      out[(size_t)(qr * 8 + b) * H_DIM + of * 16 + lr] = acc[of][r] / lsum[r];
    }
}

extern "C" void kernel_launch(void* const* d_in, const int* in_sizes, int n_in,
                              void* d_out, int out_size, void* d_ws, size_t ws_size,
                              hipStream_t stream) {
  const float* q = (const float*)d_in[0];
  const float* k = (const float*)d_in[1];
  const float* v = (const float*)d_in[2];
  // d_in[3] = mask: unused, causal mask synthesized in-kernel
  const float* Wq = (const float*)d_in[4];
  const float* Wk = (const float*)d_in[5];
  const float* Wv = (const float*)d_in[6];
  float* out = (float*)d_out;

  char* ws = (char*)d_ws;
  f16_t* Qh = (f16_t*)(ws);                                  // 4 MiB  [B][T][H]
  f16_t* Kh = (f16_t*)(ws + (4u << 20));                     // 4 MiB  [B][T][H]
  f16_t* Vt = (f16_t*)(ws + (8u << 20));                     // 4 MiB  [B][O][T]
  f16_t* Wtq = (f16_t*)(ws + (12u << 20));                   // 256 KiB [H][C]
  f16_t* Wtk = (f16_t*)(ws + (12u << 20) + (256u << 10));
  f16_t* Wtv = (f16_t*)(ws + (12u << 20) + (512u << 10));

  hipLaunchKernelGGL(wprep_kernel, dim3(3, 64), dim3(256), 0, stream, Wq, Wk, Wv, Wtq, Wtk, Wtv);
  hipLaunchKernelGGL(proj_kernel, dim3(512, 3), dim3(256), 0, stream, q, k, v, Wtq, Wtk, Wtv, Qh, Kh, Vt);
  hipLaunchKernelGGL(attn_kernel, dim3(8, 32), dim3(256), 0, stream, Qh, Kh, Vt, out);
}

// Round 9
// 124.879 us; speedup vs baseline: 1.4831x; 1.4831x over previous
//
#include <hip/hip_runtime.h>

typedef _Float16 f16_t;
typedef _Float16 f16x4 __attribute__((ext_vector_type(4)));
typedef _Float16 f16x8 __attribute__((ext_vector_type(8)));
typedef float f32x4 __attribute__((ext_vector_type(4)));

#define T_DIM 2048
#define B_DIM 8
#define C_DIM 1024
#define H_DIM 128

__device__ __forceinline__ void gload16(const void* g, void* l) {
  __builtin_amdgcn_global_load_lds((const __attribute__((address_space(1))) void*)g,
                                   (__attribute__((address_space(3))) void*)l, 16, 0, 0);
}

// ---------- Kernel 0: W [C][H] fp32 -> Wt [H][C] f16 (scale folded into Wq) ----------
__global__ __launch_bounds__(256) void wprep_kernel(
    const float* __restrict__ Wq, const float* __restrict__ Wk, const float* __restrict__ Wv,
    f16_t* __restrict__ Wtq, f16_t* __restrict__ Wtk, f16_t* __restrict__ Wtv) {
  int z = blockIdx.x;
  const float* src = (z == 0) ? Wq : (z == 1) ? Wk : Wv;
  f16_t* dst = (z == 0) ? Wtq : (z == 1) ? Wtk : Wtv;
  // scale = log2(e) / sqrt(128) folded into Wq so attention scores are in exp2 domain
  float sc = (z == 0) ? (1.4426950408889634f * 0.08838834764831845f) : 1.0f;
  int base = blockIdx.y * 2048;
  for (int i = threadIdx.x; i < 2048; i += 256) {
    int idx = base + i;
    int c = idx >> 7, h = idx & 127;
    dst[h * C_DIM + c] = (f16_t)(src[idx] * sc);
  }
}

// ---------- Kernel 1: projections — traffic-minimized GEMM (BM=128) ----------
// Model (validated R2-R8): aggregate vector-memory DEMAND caps at ~4.5-5 TB/s across
// the whole chip; timing = total demand bytes / 4.6 TB/s. So: minimize bytes.
// BM=128 -> 384 blocks -> W staged to LDS once per block = 98 MB total (vs 196 @ R2,
// 384 @ direct). A = 201 MB irreducible. Two-barrier K-loop (R2's best structure).
// 4 waves as 2x2 of 64x64, acc[4][4], LDS 37 KB.
// z=0: Qh[b][t][h], z=1: Kh[b][t][h], z=2: Vt[b][o][t]
__global__ __launch_bounds__(256) void proj_kernel(
    const float* __restrict__ qin, const float* __restrict__ kin, const float* __restrict__ vin,
    const f16_t* __restrict__ Wtq, const f16_t* __restrict__ Wtk, const f16_t* __restrict__ Wtv,
    f16_t* __restrict__ Qh, f16_t* __restrict__ Kh, f16_t* __restrict__ Vt) {
  int z = blockIdx.y;
  const float* src = (z == 0) ? qin : (z == 1) ? kin : vin;
  const f16_t* Wt = (z == 0) ? Wtq : (z == 1) ? Wtk : Wtv;

  __shared__ f16_t Alds[128][72];  // 18.4 KB
  __shared__ f16_t Wlds[128][72];  // 18.4 KB

  int tid = threadIdx.x;
  int wid = tid >> 6, lane = tid & 63, g = lane >> 4, lr = lane & 15;
  int wr = (wid >> 1) * 64, wc = (wid & 1) * 64;
  int rbase = blockIdx.x * 128;
  int srow = tid >> 3, scol = (tid & 7) * 8;  // staging: 32 rows/round, 64 cols

  const float* arp = src + (size_t)(rbase + srow) * C_DIM + scol;
  const f16_t* wrp = Wt + (size_t)srow * C_DIM + scol;

  const f32x4 z4 = {0.0f, 0.0f, 0.0f, 0.0f};
  f32x4 acc[4][4];
#pragma unroll
  for (int i = 0; i < 4; ++i)
#pragma unroll
    for (int j = 0; j < 4; ++j) acc[i][j] = z4;

  for (int kb = 0; kb < C_DIM; kb += 64) {
    __syncthreads();  // prior step's readers done
#pragma unroll
    for (int p = 0; p < 4; ++p) {
      // A: 128 rows x 64 k fp32 -> f16
      f32x4 alo = *(const f32x4*)(arp + (size_t)p * 32 * C_DIM + kb);
      f32x4 ahi = *(const f32x4*)(arp + (size_t)p * 32 * C_DIM + kb + 4);
      f16x8 h8;
      h8[0] = (f16_t)alo[0]; h8[1] = (f16_t)alo[1]; h8[2] = (f16_t)alo[2]; h8[3] = (f16_t)alo[3];
      h8[4] = (f16_t)ahi[0]; h8[5] = (f16_t)ahi[1]; h8[6] = (f16_t)ahi[2]; h8[7] = (f16_t)ahi[3];
      *(f16x8*)&Alds[p * 32 + srow][scol] = h8;
      // W: 128 rows x 64 k f16
      *(f16x8*)&Wlds[p * 32 + srow][scol] = *(const f16x8*)(wrp + (size_t)p * 32 * C_DIM + kb);
    }
    __syncthreads();
#pragma unroll
    for (int k2 = 0; k2 < 2; ++k2) {
      f16x8 af[4], wf[4];
#pragma unroll
      for (int rf = 0; rf < 4; ++rf) af[rf] = *(const f16x8*)&Alds[wr + rf * 16 + lr][k2 * 32 + g * 8];
#pragma unroll
      for (int cf = 0; cf < 4; ++cf) wf[cf] = *(const f16x8*)&Wlds[wc + cf * 16 + lr][k2 * 32 + g * 8];
#pragma unroll
      for (int rf = 0; rf < 4; ++rf)
#pragma unroll
        for (int cf = 0; cf < 4; ++cf)
          acc[rf][cf] = __builtin_amdgcn_mfma_f32_16x16x32_f16(af[rf], wf[cf], acc[rf][cf], 0, 0, 0);
    }
  }

  if (z < 2) {
    f16_t* outp = (z == 0) ? Qh : Kh;
#pragma unroll
    for (int rf = 0; rf < 4; ++rf)
#pragma unroll
      for (int cf = 0; cf < 4; ++cf)
#pragma unroll
        for (int r = 0; r < 4; ++r) {
          int rg = rbase + wr + rf * 16 + g * 4 + r;
          int t = rg >> 3, bb = rg & 7;
          int h = wc + cf * 16 + lr;
          outp[(size_t)((bb << 11) | t) * H_DIM + h] = (f16_t)acc[rf][cf][r];
        }
  } else {
#pragma unroll
    for (int rf = 0; rf < 4; ++rf)
#pragma unroll
      for (int cf = 0; cf < 4; ++cf)
#pragma unroll
        for (int r = 0; r < 4; ++r) {
          int rg = rbase + wr + rf * 16 + g * 4 + r;
          int t = rg >> 3, bb = rg & 7;
          int h = wc + cf * 16 + lr;
          Vt[((size_t)bb << 18) | ((size_t)h << 11) | (size_t)t] = (f16_t)acc[rf][cf][r];
        }
  }
}

// ---------- Kernel 2: causal flash attention, LDS-staged K/V (unchanged) ----------
__global__ __launch_bounds__(256) void attn_kernel(
    const f16_t* __restrict__ Qh, const f16_t* __restrict__ Kh, const f16_t* __restrict__ Vt,
    float* __restrict__ out) {
  int b = blockIdx.x;
  int qt = (gridDim.y - 1) - blockIdx.y;
  int tid = threadIdx.x;
  int wid = tid >> 6, lane = tid & 63, g = lane >> 4, lr = lane & 15;
  int qlo = qt * 64 + wid * 16;

  __shared__ f16_t Kl[64 * 128];
  __shared__ f16_t Vl[2][128 * 64];
  __shared__ f16_t Plds[4][16][72];

  const f16_t* Qb = Qh + ((size_t)b << 11) * H_DIM;
  const f16_t* Kb = Kh + ((size_t)b << 11) * H_DIM;
  const f16_t* Vb = Vt + ((size_t)b << 18);

  f16x8 qa[4];
#pragma unroll
  for (int c = 0; c < 4; ++c)
    qa[c] = *(const f16x8*)&Qb[(size_t)(qlo + lr) * H_DIM + c * 32 + g * 8];

  const f32x4 z4 = {0.0f, 0.0f, 0.0f, 0.0f};
  float mrow[4], lsum[4];
  f32x4 acc[8];
#pragma unroll
  for (int r = 0; r < 4; ++r) { mrow[r] = -1e30f; lsum[r] = 0.0f; }
#pragma unroll
  for (int of = 0; of < 8; ++of) acc[of] = z4;

  int ntiles = qt + 1;

  auto stageK = [&](int kt) {
    const char* base = (const char*)(Kb + (size_t)(kt * 64) * H_DIM);
#pragma unroll
    for (int i = 0; i < 4; ++i) {
      int chunk = wid * 4 + i;
      int q = chunk * 1024 + lane * 16;
      int p = q ^ (((q >> 8) & 7) << 4);
      gload16(base + p, (char*)&Kl[0] + q);
    }
  };
  auto stageV = [&](int bufi, int kt) {
#pragma unroll
    for (int i = 0; i < 4; ++i) {
      int chunk = wid * 4 + i;
      int q = chunk * 1024 + lane * 16;
      int p = q ^ (((q >> 7) & 7) << 4);
      int row = p >> 7;
      int colb = p & 127;
      const char* src = (const char*)(Vb + (size_t)row * T_DIM + kt * 64) + colb;
      gload16(src, (char*)&Vl[bufi][0] + q);
    }
  };

  stageK(0);
  stageV(0, 0);
  __syncthreads();
  int vcur = 0;

  for (int kt = 0; kt < ntiles; ++kt) {
    int kb = kt * 64;
    bool more = (kt + 1 < ntiles);
    if (more) stageV(vcur ^ 1, kt + 1);

    f32x4 s[4];
#pragma unroll
    for (int cf = 0; cf < 4; ++cf) s[cf] = z4;
    const char* Kbuf = (const char*)&Kl[0];
#pragma unroll
    for (int cf = 0; cf < 4; ++cf) {
      int row = cf * 16 + lr;
#pragma unroll
      for (int c = 0; c < 4; ++c) {
        int linb = row * 256 + c * 64 + g * 16;
        f16x8 kf = *(const f16x8*)(Kbuf + (linb ^ ((row & 7) << 4)));
        s[cf] = __builtin_amdgcn_mfma_f32_16x16x32_f16(qa[c], kf, s[cf], 0, 0, 0);
      }
    }
    __syncthreads();
    if (more) stageK(kt + 1);

    if (kb + 63 > qlo) {
#pragma unroll
      for (int cf = 0; cf < 4; ++cf) {
        int kcol = kb + cf * 16 + lr;
#pragma unroll
        for (int r = 0; r < 4; ++r)
          if (kcol > qlo + g * 4 + r) s[cf][r] = -1e30f;
      }
    }
    float cand[4], mnew[4], al[4], rs[4];
#pragma unroll
    for (int r = 0; r < 4; ++r)
      cand[r] = fmaxf(fmaxf(s[0][r], s[1][r]), fmaxf(s[2][r], s[3][r]));
#pragma unroll
    for (int d = 1; d <= 8; d <<= 1)
#pragma unroll
      for (int r = 0; r < 4; ++r)
        cand[r] = fmaxf(cand[r], __shfl_xor(cand[r], d));
    float p[4][4];
#pragma unroll
    for (int r = 0; r < 4; ++r) {
      mnew[r] = fmaxf(mrow[r], cand[r]);
      al[r] = exp2f(mrow[r] - mnew[r]);
      mrow[r] = mnew[r];
    }
#pragma unroll
    for (int cf = 0; cf < 4; ++cf)
#pragma unroll
      for (int r = 0; r < 4; ++r)
        p[cf][r] = exp2f(s[cf][r] - mnew[r]);
#pragma unroll
    for (int r = 0; r < 4; ++r)
      rs[r] = (p[0][r] + p[1][r]) + (p[2][r] + p[3][r]);
#pragma unroll
    for (int d = 1; d <= 8; d <<= 1)
#pragma unroll
      for (int r = 0; r < 4; ++r)
        rs[r] += __shfl_xor(rs[r], d);
#pragma unroll
    for (int r = 0; r < 4; ++r)
      lsum[r] = lsum[r] * al[r] + rs[r];
#pragma unroll
    for (int of = 0; of < 8; ++of)
#pragma unroll
      for (int r = 0; r < 4; ++r)
        acc[of][r] *= al[r];
#pragma unroll
    for (int cf = 0; cf < 4; ++cf)
#pragma unroll
      for (int r = 0; r < 4; ++r)
        Plds[wid][g * 4 + r][cf * 16 + lr] = (f16_t)p[cf][r];
    asm volatile("s_waitcnt lgkmcnt(0)" ::: "memory");
    __builtin_amdgcn_sched_barrier(0);
    f16x8 pa[2];
#pragma unroll
    for (int c = 0; c < 2; ++c)
      pa[c] = *(const f16x8*)&Plds[wid][lr][c * 32 + g * 8];

    const char* Vbuf = (const char*)&Vl[vcur][0];
#pragma unroll
    for (int c = 0; c < 2; ++c)
#pragma unroll
      for (int of = 0; of < 8; ++of) {
        int row = of * 16 + lr;
        int linb = row * 128 + c * 64 + g * 16;
        f16x8 vf = *(const f16x8*)(Vbuf + (linb ^ ((row & 7) << 4)));
        acc[of] = __builtin_amdgcn_mfma_f32_16x16x32_f16(pa[c], vf, acc[of], 0, 0, 0);
      }
    __syncthreads();
    vcur ^= 1;
  }

#pragma unroll
  for (int of = 0; of < 8; ++of)
#pragma unroll
    for (int r = 0; r < 4; ++r) {
      int qr = qlo + g * 4 + r;
      out[(size_t)(qr * 8 + b) * H_DIM + of * 16 + lr] = acc[of][r] / lsum[r];
    }
}

extern "C" void kernel_launch(void* const* d_in, const int* in_sizes, int n_in,
                              void* d_out, int out_size, void* d_ws, size_t ws_size,
                              hipStream_t stream) {
  const float* q = (const float*)d_in[0];
  const float* k = (const float*)d_in[1];
  const float* v = (const float*)d_in[2];
  // d_in[3] = mask: unused, causal mask synthesized in-kernel
  const float* Wq = (const float*)d_in[4];
  const float* Wk = (const float*)d_in[5];
  const float* Wv = (const float*)d_in[6];
  float* out = (float*)d_out;

  char* ws = (char*)d_ws;
  f16_t* Qh = (f16_t*)(ws);                                  // 4 MiB  [B][T][H]
  f16_t* Kh = (f16_t*)(ws + (4u << 20));                     // 4 MiB  [B][T][H]
  f16_t* Vt = (f16_t*)(ws + (8u << 20));                     // 4 MiB  [B][O][T]
  f16_t* Wtq = (f16_t*)(ws + (12u << 20));                   // 256 KiB [H][C]
  f16_t* Wtk = (f16_t*)(ws + (12u << 20) + (256u << 10));
  f16_t* Wtv = (f16_t*)(ws + (12u << 20) + (512u << 10));

  hipLaunchKernelGGL(wprep_kernel, dim3(3, 64), dim3(256), 0, stream, Wq, Wk, Wv, Wtq, Wtk, Wtv);
  hipLaunchKernelGGL(proj_kernel, dim3(128, 3), dim3(256), 0, stream, q, k, v, Wtq, Wtk, Wtv, Qh, Kh, Vt);
  hipLaunchKernelGGL(attn_kernel, dim3(8, 32), dim3(256), 0, stream, Qh, Kh, Vt, out);
}